// Round 6
// baseline (1106.086 us; speedup 1.0000x reference)
//
#include <hip/hip_runtime.h>
#include <hip/hip_bf16.h>

typedef short bf16x8 __attribute__((ext_vector_type(8)));
typedef float f32x4  __attribute__((ext_vector_type(4)));
typedef int   i32x4  __attribute__((ext_vector_type(4)));

#define N_PTS  1000000
#define K_VOL  27
#define C_IN   64
#define C_OUT  64
#define ROWS_PER_BLOCK 256           // 4 waves x 4 row-tiles x 16 rows
#define KS     14                    // k-chunk staged in LDS (phase0:14, phase1:13)

static __device__ __forceinline__ short f2bf(float x) {
    __hip_bfloat16 h = __float2bfloat16(x);
    return *(short*)&h;
}

// ---------------------------------------------------------------------------
// Convert features fp32 [N][64] -> bf16 [N][64] in ws. 8 elems per thread.
// ---------------------------------------------------------------------------
__global__ __launch_bounds__(256) void cvt_feat(const float* __restrict__ f,
                                                __hip_bfloat16* __restrict__ o,
                                                int n8) {
    int id = blockIdx.x * 256 + threadIdx.x;
    if (id >= n8) return;
    const float4* src = (const float4*)f;
    float4 a = src[id * 2 + 0];
    float4 b = src[id * 2 + 1];
    bf16x8 v;
    v[0] = f2bf(a.x); v[1] = f2bf(a.y); v[2] = f2bf(a.z); v[3] = f2bf(a.w);
    v[4] = f2bf(b.x); v[5] = f2bf(b.y); v[6] = f2bf(b.z); v[7] = f2bf(b.w);
    ((bf16x8*)o)[id] = v;
}

// ---------------------------------------------------------------------------
// Repack W fp32 [27][64][64] (k, ci, co) -> bf16 MFMA-B-fragment order.
// chunk id = k*512 + s*256 + t*64 + lane  (s = k-step 0/1, t = col-tile 0..3)
// elem j of chunk = W[k][s*32 + (lane>>4)*8 + j][t*16 + (lane&15)]
// ---------------------------------------------------------------------------
__global__ void repack_w(const float* __restrict__ W,
                         __hip_bfloat16* __restrict__ outw) {
    int id = blockIdx.x * 256 + threadIdx.x;          // 0 .. 27*2*4*64-1
    if (id >= K_VOL * 2 * 4 * 64) return;
    int lane = id & 63;
    int t    = (id >> 6) & 3;
    int s    = (id >> 8) & 1;
    int k    = id >> 9;
    int ci0  = s * 32 + (lane >> 4) * 8;
    int co   = t * 16 + (lane & 15);
    const float* src = W + (k * C_IN + ci0) * C_OUT + co;
    bf16x8 v;
#pragma unroll
    for (int j = 0; j < 8; ++j) v[j] = f2bf(src[j * C_OUT]);
    ((bf16x8*)outw)[id] = v;
}

// ---------------------------------------------------------------------------
// Stage pre-masked indices for k-range [kb, kb+KN) into s_idx[row*KS + kk].
// ---------------------------------------------------------------------------
template<int KN>
static __device__ __forceinline__ void stage_sidx(int* s_idx,
                                                  const int* __restrict__ kmap,
                                                  const int* __restrict__ kmask,
                                                  int base27, int kb,
                                                  int tid, int lastrow) {
    for (int i = tid; i < ROWS_PER_BLOCK * KN; i += 256) {
        int row = i / KN;            // magic-mul (KN compile-time)
        int kk  = i - row * KN;
        int r   = -1;
        if (row < lastrow) {
            int gi = base27 + row * K_VOL + kb + kk;
            int m  = kmask[gi];
            r = m ? kmap[gi] : -1;
        }
        s_idx[row * KS + kk] = r;
    }
}

// ---------------------------------------------------------------------------
// Main gather-GEMM. Block = 256 rows x 64 cols. 4 waves; each wave owns
// 64 rows as 4 row-tiles of 16, with 4x4 mfma_f32_16x16x32_bf16 accumulators.
// B fragments are DEDUPLICATED through LDS: per k each wave loads only 2 of
// the 8 chunks from global (prefetched for k+1 at top of iter k, ds_written
// after the MFMAs - T14 issue-early/write-late), all waves ds_read the shared
// copy. Global VMEM per wave-k: 16 -> 10 instructions.
// ---------------------------------------------------------------------------
__global__ __launch_bounds__(256, 4) void sconv_kernel(
    const __hip_bfloat16* __restrict__ feat,
    const int* __restrict__ kmap,
    const int* __restrict__ kmask,
    const __hip_bfloat16* __restrict__ wfrag,
    float* __restrict__ out) {

    __shared__ int   s_idx[ROWS_PER_BLOCK * KS];   // 14336 B
    __shared__ short s_b[2][8 * 512];              // 2 x 8 KiB ping-pong B

    const int tid = threadIdx.x;
    const int rb  = blockIdx.x * ROWS_PER_BLOCK;
    const int base27  = rb * K_VOL;                // < 2^31
    const int lastrow = min(ROWS_PER_BLOCK, N_PTS - rb);

    const int lane = tid & 63;
    const int wave = tid >> 6;
    const int mrow = lane & 15;     // A row within a 16-row tile / C col
    const int g    = lane >> 4;     // A k-quad: ci slice g*8..g*8+7

    const bf16x8* __restrict__ f8 = (const bf16x8*)feat;
    const bf16x8* __restrict__ w8 = (const bf16x8*)wfrag;

    // my two B chunks (c = s*4+t in 0..7): global chunk = k*512 + c*64 + lane
    const int c0 = wave * 2 + 0;
    const int c1 = wave * 2 + 1;

    // ---- prologue: B(0) -> s_b[0]; stage s_idx phase 0 ----
    {
        bf16x8 br0 = w8[c0 * 64 + lane];
        bf16x8 br1 = w8[c1 * 64 + lane];
        ((bf16x8*)s_b[0])[c0 * 64 + lane] = br0;
        ((bf16x8*)s_b[0])[c1 * 64 + lane] = br1;
    }
    stage_sidx<KS>(s_idx, kmap, kmask, base27, 0, tid, lastrow);
    __syncthreads();

    f32x4 acc[4][4];
#pragma unroll
    for (int t = 0; t < 4; ++t)
#pragma unroll
        for (int c = 0; c < 4; ++c) acc[t][c] = (f32x4){0.f, 0.f, 0.f, 0.f};

    // lane's index base: row_local = wave*64 + t*16 + mrow, stride KS
    const int* sidx = s_idx + (wave * 64 + mrow) * KS;

#pragma unroll
    for (int ph = 0; ph < 2; ++ph) {
        const int kb = ph ? KS : 0;
        const int kn = ph ? (K_VOL - KS) : KS;
        if (ph) {
            // all waves passed k=KS-1's trailing barrier -> safe to overwrite
            stage_sidx<K_VOL - KS>(s_idx, kmap, kmask, base27, KS, tid, lastrow);
            __syncthreads();
        }
#pragma unroll 1
        for (int kk = 0; kk < kn; ++kk) {
            const int k   = kb + kk;
            const int cur = k & 1;
            const bool pf = (k + 1 < K_VOL);

            // 1) prefetch my 2 B(k+1) chunks to regs (landed during MFMAs)
            bf16x8 br0, br1;
            if (pf) {
                const bf16x8* wn = w8 + (size_t)(k + 1) * 512;
                br0 = wn[c0 * 64 + lane];
                br1 = wn[c1 * 64 + lane];
            }

            // 2) gathers for k (guarded: masked lanes issue no requests)
            bf16x8 a0[4], a1[4];
#pragma unroll
            for (int t = 0; t < 4; ++t) {
                int idx = sidx[t * 16 * KS + kk];
                a0[t] = (bf16x8){0, 0, 0, 0, 0, 0, 0, 0};
                a1[t] = (bf16x8){0, 0, 0, 0, 0, 0, 0, 0};
                if (idx >= 0) {
                    const bf16x8* fr = f8 + (size_t)idx * 8 + g;
                    a0[t] = fr[0];   // ci = g*8 .. g*8+7     (s=0)
                    a1[t] = fr[4];   // ci = 32 + g*8 .. +7   (s=1)
                }
            }

            // 3) B(k) from LDS, two halves to limit live range
            const bf16x8* sb = (const bf16x8*)s_b[cur];
            {
                bf16x8 b00 = sb[0 * 64 + lane];
                bf16x8 b01 = sb[1 * 64 + lane];
                bf16x8 b02 = sb[2 * 64 + lane];
                bf16x8 b03 = sb[3 * 64 + lane];
#pragma unroll
                for (int t = 0; t < 4; ++t) {
                    acc[t][0] = __builtin_amdgcn_mfma_f32_16x16x32_bf16(a0[t], b00, acc[t][0], 0, 0, 0);
                    acc[t][1] = __builtin_amdgcn_mfma_f32_16x16x32_bf16(a0[t], b01, acc[t][1], 0, 0, 0);
                    acc[t][2] = __builtin_amdgcn_mfma_f32_16x16x32_bf16(a0[t], b02, acc[t][2], 0, 0, 0);
                    acc[t][3] = __builtin_amdgcn_mfma_f32_16x16x32_bf16(a0[t], b03, acc[t][3], 0, 0, 0);
                }
            }
            {
                bf16x8 b10 = sb[4 * 64 + lane];
                bf16x8 b11 = sb[5 * 64 + lane];
                bf16x8 b12 = sb[6 * 64 + lane];
                bf16x8 b13 = sb[7 * 64 + lane];
#pragma unroll
                for (int t = 0; t < 4; ++t) {
                    acc[t][0] = __builtin_amdgcn_mfma_f32_16x16x32_bf16(a1[t], b10, acc[t][0], 0, 0, 0);
                    acc[t][1] = __builtin_amdgcn_mfma_f32_16x16x32_bf16(a1[t], b11, acc[t][1], 0, 0, 0);
                    acc[t][2] = __builtin_amdgcn_mfma_f32_16x16x32_bf16(a1[t], b12, acc[t][2], 0, 0, 0);
                    acc[t][3] = __builtin_amdgcn_mfma_f32_16x16x32_bf16(a1[t], b13, acc[t][3], 0, 0, 0);
                }
            }

            // 4) write prefetched B(k+1) into the other buffer (write-late)
            if (pf) {
                ((bf16x8*)s_b[cur ^ 1])[c0 * 64 + lane] = br0;
                ((bf16x8*)s_b[cur ^ 1])[c1 * 64 + lane] = br1;
            }
            __syncthreads();   // flip: writes visible, reads of s_b[cur] done
        }
    }

    // Epilogue. C/D layout (verified m89/m91): col = lane&15, row = (lane>>4)*4 + reg
    const int orow0 = rb + wave * 64 + g * 4;
#pragma unroll
    for (int t = 0; t < 4; ++t) {
        const int rowb = orow0 + t * 16;
#pragma unroll
        for (int j = 0; j < 4; ++j) {
            const int row = rowb + j;
            if (row < N_PTS) {
                size_t r = (size_t)row * C_OUT + mrow;
                out[r +  0] = acc[t][0][j];
                out[r + 16] = acc[t][1][j];
                out[r + 32] = acc[t][2][j];
                out[r + 48] = acc[t][3][j];
            }
        }
    }
}

extern "C" void kernel_launch(void* const* d_in, const int* in_sizes, int n_in,
                              void* d_out, int out_size, void* d_ws, size_t ws_size,
                              hipStream_t stream) {
    const float* feat32 = (const float*)d_in[0];   // [1e6][64] fp32
    const float* W      = (const float*)d_in[1];   // [27][64][64] fp32
    const int*   kmap   = (const int*)d_in[2];     // [1e6][27] int32
    const int*   kmask  = (const int*)d_in[3];     // [1e6][27] int32
    float*       out    = (float*)d_out;           // [1e6][64] fp32

    // ws layout: [0, 128MB) bf16 features; then 221184 B repacked bf16 W
    __hip_bfloat16* featbf = (__hip_bfloat16*)d_ws;
    __hip_bfloat16* wfrag  = (__hip_bfloat16*)((char*)d_ws +
                              (size_t)N_PTS * C_IN * sizeof(__hip_bfloat16));

    const int n8 = N_PTS * C_IN / 8;               // 8e6 chunks of 8 elems
    cvt_feat<<<(n8 + 255) / 256, 256, 0, stream>>>(feat32, featbf, n8);

    const int repack_threads = K_VOL * 2 * 4 * 64; // 13824
    repack_w<<<(repack_threads + 255) / 256, 256, 0, stream>>>(W, wfrag);

    const int nblocks = (N_PTS + ROWS_PER_BLOCK - 1) / ROWS_PER_BLOCK; // 3907
    sconv_kernel<<<nblocks, 256, 0, stream>>>(featbf, kmap, kmask, wfrag, out);
}